// Round 9
// baseline (1380.811 us; speedup 1.0000x reference)
//
#include <hip/hip_runtime.h>
#include <hip/hip_bf16.h>
#include <math.h>

#define LNUM 12
#define BNUM 8
#define DNUM 2048
#define VNUM 32000
#define HNUM 64
#define HDNUM 64
#define GNUM 8
#define NNUM 128
#define KNUM 4
#define INUM (HNUM*HDNUM)              /* 4096 */
#define CONVNUM (INUM + 2*GNUM*NNUM)   /* 6144 */
#define PNUM (INUM + CONVNUM + HNUM)   /* 10304 (not 14304! 41 strips survive) */

#define IP_KC 16                       /* in_proj row chunks (128 rows) */
#define NSTRIP 41                      /* ceil(PNUM/256) */
#define A_TILES (NSTRIP*IP_KC)         /* 656 */
#define GRID 1024                      /* 4 blocks/CU resident by construction */

struct MParams {
  const int* ids;
  const float* conv_states; const float* ssm_states;
  const float* emb; const float* norm_w; const float* in_proj_w;
  const float* conv_w; const float* conv_b; const float* dt_bias;
  const float* A_log; const float* D_param; const float* gn_w;
  const float* out_proj_w;
  float* conv_out_st; float* ssm_out_st;
  float* h; float* yg; float* ygsq; float* sqp; float* part1;
  int* flagE; int* flagS; int* flagA; int* flagC; int* flagD;
};

__device__ __forceinline__ float sigmoidf_(float x){ return 1.f/(1.f+expf(-x)); }

// Agent-scope (MALL-direct) accesses — bypass non-coherent per-XCD L2.
__device__ __forceinline__ int   uc_load_i (const int* p){ return __hip_atomic_load((int*)p, __ATOMIC_RELAXED, __HIP_MEMORY_SCOPE_AGENT); }
__device__ __forceinline__ float uc_load_f (const float* p){ return __hip_atomic_load((float*)p, __ATOMIC_RELAXED, __HIP_MEMORY_SCOPE_AGENT); }
__device__ __forceinline__ void  uc_store_f(float* p, float v){ __hip_atomic_store(p, v, __ATOMIC_RELAXED, __HIP_MEMORY_SCOPE_AGENT); }
__device__ __forceinline__ void  uc_add_f  (float* p, float v){ __hip_atomic_fetch_add(p, v, __ATOMIC_RELAXED, __HIP_MEMORY_SCOPE_AGENT); }
__device__ __forceinline__ void  uc_inc_i  (int* p){ __hip_atomic_fetch_add(p, 1, __ATOMIC_RELAXED, __HIP_MEMORY_SCOPE_AGENT); }

// Producer-side: all block's stores drained (per-wave vmcnt drain at s_barrier),
// then one atomic inc on this flag's dedicated cacheline.
__device__ __forceinline__ void flag_inc(int* line){
  __syncthreads();
  if (threadIdx.x == 0){
    asm volatile("s_waitcnt vmcnt(0) lgkmcnt(0)" ::: "memory");
    uc_inc_i(line);
  }
}

// Consumer-side: single-line wait (read-polls; reads to one line scale).
__device__ __forceinline__ void wait_line(const int* line, int target){
  if (threadIdx.x == 0){
    long sp = 0;
    while (uc_load_i(line) < target){
      __builtin_amdgcn_s_sleep(4);
      if (++sp > (1L<<19)) break;   // failsafe: wrong answer beats a hang
    }
  }
  __syncthreads();
}

// Consumer-side: sum of 32 group counters (stride 16 ints) >= target.
__device__ __forceinline__ void wait_grp(const int* grp, int target){
  __shared__ int done_s;
  if (threadIdx.x == 0) done_s = 0;
  __syncthreads();
  long sp = 0;
  for (;;){
    if (threadIdx.x < 64){
      int v = (threadIdx.x < 32) ? uc_load_i(&grp[threadIdx.x*16]) : 0;
      v += __shfl_xor(v,1); v += __shfl_xor(v,2); v += __shfl_xor(v,4);
      v += __shfl_xor(v,8); v += __shfl_xor(v,16); v += __shfl_xor(v,32);
      if (threadIdx.x == 0) done_s = (v >= target);
    }
    __syncthreads();
    if (done_s || ++sp > (1L<<18)) break;
    __builtin_amdgcn_s_sleep(4);
    __syncthreads();
  }
}

__global__ __launch_bounds__(256, 4) void k_mamba(MParams P){
  const int blk = blockIdx.x, t = threadIdx.x;
  const int w = t >> 6, l = t & 63;
  __shared__ float smem[8256];   // 33 KB: phase-dependent layout (4 blk/CU = 132KB <= 160)

  // ---------------- embed ----------------
  if (blk < BNUM){
    int b = blk;
    const float* src = P.emb + (size_t)P.ids[b]*DNUM;
    float* dst = P.h + (size_t)b*DNUM;
    float4 v0 = *(const float4*)(src + t*4);
    float4 v1 = *(const float4*)(src + 1024 + t*4);
    uc_store_f(dst + t*4 + 0, v0.x); uc_store_f(dst + t*4 + 1, v0.y);
    uc_store_f(dst + t*4 + 2, v0.z); uc_store_f(dst + t*4 + 3, v0.w);
    uc_store_f(dst + 1024 + t*4 + 0, v1.x); uc_store_f(dst + 1024 + t*4 + 1, v1.y);
    uc_store_f(dst + 1024 + t*4 + 2, v1.z); uc_store_f(dst + 1024 + t*4 + 3, v1.w);
    flag_inc(P.flagE);
  }

  for (int li = 0; li < LNUM; ++li){
    const float* Wi   = P.in_proj_w  + (size_t)li*DNUM*PNUM;
    const float* nw   = P.norm_w     + (size_t)li*DNUM;
    const float* cw   = P.conv_w     + (size_t)li*CONVNUM*KNUM;
    const float* cb   = P.conv_b     + (size_t)li*CONVNUM;
    const float* db   = P.dt_bias    + (size_t)li*HNUM;
    const float* al   = P.A_log      + (size_t)li*HNUM;
    const float* dpp  = P.D_param    + (size_t)li*HNUM;
    const float* gw   = P.gn_w       + (size_t)li*INUM;
    const float* Wo   = P.out_proj_w + (size_t)li*INUM*DNUM;
    const float* csin = P.conv_states + (size_t)li*BNUM*CONVNUM*KNUM;
    float*       csout= P.conv_out_st + (size_t)li*BNUM*CONVNUM*KNUM;
    const float* ssin = P.ssm_states  + (size_t)li*BNUM*HNUM*HDNUM*NNUM;
    float*       ssout= P.ssm_out_st  + (size_t)li*BNUM*HNUM*HDNUM*NNUM;

    // ---- layer entry: h (and all prior-layer state) ready ----
    if (li == 0) wait_line(P.flagE, BNUM);
    else         wait_grp(P.flagD + (li-1)*512, GRID);

    // ---- Phase A: in_proj GEMV (unnormalized inputs scaled by nw; 1/rms deferred
    //      to C). 656 tiles (41 strips x 16 chunks) + 8 sqp blocks. ----
    if (blk < A_TILES){
      float*  xs  = smem;                    // 1024
      float4* red = (float4*)(smem + 1040);  // 512 float4
      int pb = blk % NSTRIP, kc = blk / NSTRIP;
      int r0 = kc*128;
      for (int i = t; i < BNUM*128; i += 256){
        int b = i>>7, dl = i&127;
        xs[i] = uc_load_f(&P.h[b*DNUM + r0 + dl]) * nw[r0 + dl];
      }
      __syncthreads();
      int p0 = pb*256 + l*4;
      bool valid = (p0 < PNUM);
      float4 acc[BNUM];
      #pragma unroll
      for (int b = 0; b < BNUM; ++b) acc[b] = make_float4(0.f,0.f,0.f,0.f);
      if (valid){
        int rbase = w*32;
        const float* wp = Wi + (size_t)(r0 + rbase)*PNUM + p0;
        #pragma unroll 4
        for (int r = 0; r < 32; ++r){
          float4 w4 = *(const float4*)wp;
          wp += PNUM;
          #pragma unroll
          for (int b = 0; b < BNUM; ++b){
            float xvv = xs[b*128 + rbase + r];
            acc[b].x += xvv*w4.x; acc[b].y += xvv*w4.y; acc[b].z += xvv*w4.z; acc[b].w += xvv*w4.w;
          }
        }
      }
      #pragma unroll
      for (int rw = 1; rw < 4; ++rw){
        if (w == rw){
          #pragma unroll
          for (int b = 0; b < BNUM; ++b) red[b*64 + l] = acc[b];
        }
        __syncthreads();
        if (w == 0){
          #pragma unroll
          for (int b = 0; b < BNUM; ++b){
            float4 r4 = red[b*64 + l];
            acc[b].x += r4.x; acc[b].y += r4.y; acc[b].z += r4.z; acc[b].w += r4.w;
          }
        }
        __syncthreads();
      }
      if (w == 0){
        #pragma unroll
        for (int b = 0; b < BNUM; ++b) red[b*64 + l] = acc[b];
      }
      __syncthreads();
      const float* redf = (const float*)red;
      if (pb*256 + t < PNUM){
        #pragma unroll
        for (int b = 0; b < BNUM; ++b)
          uc_store_f(&P.part1[(size_t)(kc*BNUM + b)*PNUM + pb*256 + t], redf[b*256 + t]);
      }
      flag_inc(&P.flagA[li*896 + pb*16]);
    } else if (blk < A_TILES + BNUM){
      int b = blk - A_TILES;
      float q = 0.f;
      for (int i = t; i < DNUM; i += 256){
        float v = uc_load_f(&P.h[b*DNUM + i]);
        q += v*v;
      }
      q += __shfl_xor(q,32); q += __shfl_xor(q,16); q += __shfl_xor(q,8);
      q += __shfl_xor(q,4);  q += __shfl_xor(q,2);  q += __shfl_xor(q,1);
      if (l == 0) smem[w] = q;
      __syncthreads();
      if (t == 0) uc_store_f(&P.sqp[b], smem[0]+smem[1]+smem[2]+smem[3]);
      flag_inc(&P.flagS[li*16]);
    }

    // ---- Phase C: reduce part1 (x inv) + conv/silu/dt + SSM + gate.
    //      1024 tiles = 8 b x 64 heads x 2 half-heads. ----
    {
      int b = blk >> 7, rest = blk & 127, hh = rest >> 1, half = rest & 1, g = hh >> 3;
      // wait on the 5 producer strips + sqp
      {
        int s_g = (hh*HDNUM + half*32) >> 8;
        int s_x = (INUM + hh*HDNUM + half*32) >> 8;
        int s_B = (2*INUM + g*NNUM) >> 8;
        int s_C = (2*INUM + GNUM*NNUM + g*NNUM) >> 8;
        int s_dt = (INUM + CONVNUM) >> 8;   // 40
        const int* line = nullptr; int tgt = IP_KC;
        if      (t == 0) line = &P.flagA[li*896 + s_g*16];
        else if (t == 1) line = &P.flagA[li*896 + s_x*16];
        else if (t == 2) line = &P.flagA[li*896 + s_B*16];
        else if (t == 3) line = &P.flagA[li*896 + s_C*16];
        else if (t == 4) line = &P.flagA[li*896 + s_dt*16];
        else if (t == 5){ line = &P.flagS[li*16]; tgt = BNUM; }
        if (line){
          long sp = 0;
          while (uc_load_i(line) < tgt){
            __builtin_amdgcn_s_sleep(4);
            if (++sp > (1L<<19)) break;
          }
        }
        __syncthreads();
      }
      float* xv    = smem;        // 32
      float* gatel = smem + 32;   // 32
      float* Bsh   = smem + 64;   // 128
      float* Csh   = smem + 192;  // 128
      float* scal  = smem + 320;  // [0]=dt [1]=dA [2]=inv
      float* sred  = smem + 328;  // 8
      if (t == 0) scal[2] = rsqrtf(uc_load_f(&P.sqp[b]) * (1.f/DNUM) + 1e-5f);
      __syncthreads();
      float inv = scal[2];
      // pass 1: B (t<128) | C (t>=128)
      {
        int n = t & 127;
        int c = (t < 128) ? (INUM + g*NNUM + n) : (INUM + GNUM*NNUM + g*NNUM + n);
        int p = INUM + c;
        float v = 0.f;
        #pragma unroll
        for (int kc2 = 0; kc2 < IP_KC; ++kc2) v += uc_load_f(&P.part1[(size_t)(kc2*BNUM + b)*PNUM + p]);
        v *= inv;
        size_t sid = (size_t)b*CONVNUM + c;
        float4 s4 = *(const float4*)(csin + sid*KNUM);
        float4 ns = make_float4(s4.y, s4.z, s4.w, v);
        if ((hh & 7) == 0 && half == 0) *(float4*)(csout + sid*KNUM) = ns;
        float4 w4 = *(const float4*)(cw + (size_t)c*KNUM);
        float co = ns.x*w4.x + ns.y*w4.y + ns.z*w4.z + ns.w*w4.w + cb[c];
        float sv = co * sigmoidf_(co);
        if (t < 128) Bsh[n] = sv; else Csh[n] = sv;
      }
      // pass 2: x(32) | gate(32) | dt(1)
      if (t < 32){
        int hd = half*32 + t;
        int c = hh*HDNUM + hd;
        int p = INUM + c;
        float v = 0.f;
        #pragma unroll
        for (int kc2 = 0; kc2 < IP_KC; ++kc2) v += uc_load_f(&P.part1[(size_t)(kc2*BNUM + b)*PNUM + p]);
        v *= inv;
        size_t sid = (size_t)b*CONVNUM + c;
        float4 s4 = *(const float4*)(csin + sid*KNUM);
        float4 ns = make_float4(s4.y, s4.z, s4.w, v);
        *(float4*)(csout + sid*KNUM) = ns;
        float4 w4 = *(const float4*)(cw + (size_t)c*KNUM);
        float co = ns.x*w4.x + ns.y*w4.y + ns.z*w4.z + ns.w*w4.w + cb[c];
        xv[t] = co * sigmoidf_(co);
      } else if (t < 64){
        int hd = half*32 + (t-32);
        int p = hh*HDNUM + hd;
        float v = 0.f;
        #pragma unroll
        for (int kc2 = 0; kc2 < IP_KC; ++kc2) v += uc_load_f(&P.part1[(size_t)(kc2*BNUM + b)*PNUM + p]);
        gatel[t-32] = v * inv;
      } else if (t == 64){
        int p = INUM + CONVNUM + hh;
        float v = 0.f;
        #pragma unroll
        for (int kc2 = 0; kc2 < IP_KC; ++kc2) v += uc_load_f(&P.part1[(size_t)(kc2*BNUM + b)*PNUM + p]);
        float dtr = v*inv + db[hh];
        float dt = (dtr > 20.f) ? dtr : log1pf(expf(dtr));
        dt = fminf(dt, 10000.f);
        scal[0] = dt;
        scal[1] = expf(dt * (-expf(al[hh])));
      }
      __syncthreads();
      float dt = scal[0], dA = scal[1], dp = dpp[hh];
      int r = t & 31, a2 = t >> 5;
      float4 Bv = *(float4*)&Bsh[r*4];
      float4 Cv = *(float4*)&Csh[r*4];
      const float* si = ssin  + (size_t)(b*HNUM + hh)*HDNUM*NNUM + half*4096;
      float*       so = ssout + (size_t)(b*HNUM + hh)*HDNUM*NNUM + half*4096;
      float s_yg = 0.f;
      #pragma unroll
      for (int k = 0; k < 4; ++k){
        int hdl = k*8 + a2;
        float xvv = xv[hdl];
        float coef = dt * xvv;
        int off = k*1024 + t*4;
        float4 s4 = *(const float4*)(si + off);
        float4 ns;
        ns.x = s4.x*dA + coef*Bv.x;
        ns.y = s4.y*dA + coef*Bv.y;
        ns.z = s4.z*dA + coef*Bv.z;
        ns.w = s4.w*dA + coef*Bv.w;
        *(float4*)(so + off) = ns;
        float yp = ns.x*Cv.x + ns.y*Cv.y + ns.z*Cv.z + ns.w*Cv.w;
        yp += __shfl_xor(yp,1); yp += __shfl_xor(yp,2); yp += __shfl_xor(yp,4);
        yp += __shfl_xor(yp,8); yp += __shfl_xor(yp,16);
        if (r == 0){
          float gv = gatel[hdl];
          float ygv = (yp + xvv*dp) * gv * sigmoidf_(gv);
          uc_store_f(&P.yg[b*INUM + hh*HDNUM + half*32 + hdl], ygv);
          s_yg += ygv*ygv;
        }
      }
      if (r == 0) sred[a2] = s_yg;
      __syncthreads();
      if (t == 0){
        float tot = 0.f;
        #pragma unroll
        for (int j = 0; j < 8; ++j) tot += sred[j];
        uc_store_f(&P.ygsq[b*128 + hh*2 + half], tot);
      }
      flag_inc(&P.flagC[li*512 + (blk>>5)*16]);
    }

    // ---- Phase D: out_proj GEMV (gated norm fused), atomicAdd into h.
    //      1024 tiles = 128 col-strips (16 cols) x 8 row-chunks (512 rows).
    //      Only 8 adds per h element (was 64). ----
    {
      wait_grp(P.flagC + li*512, GRID);
      float*  xs   = smem;                     // 4096
      float*  invg = smem + 4096;              // 8 (+pad)
      float2* red2 = (float2*)(smem + 4112);   // 32 rowgrp x 8 colpair x 8 b
      int pb = blk & 127, kc = blk >> 7;
      int c0 = pb*16, r0 = kc*512;
      if (t < 64){
        int b2 = t>>3, j = t&7;
        float v = 0.f;
        #pragma unroll
        for (int jj = 0; jj < 16; ++jj) v += uc_load_f(&P.ygsq[b2*128 + j + jj*8]);
        v += __shfl_xor(v,1); v += __shfl_xor(v,2); v += __shfl_xor(v,4);
        if (j == 0) invg[b2] = rsqrtf(v*(1.f/INUM) + 1e-5f);
      }
      __syncthreads();
      for (int i = t; i < BNUM*512; i += 256){
        int b = i>>9, il = i&511;
        xs[i] = uc_load_f(&P.yg[b*INUM + r0 + il]) * invg[b] * gw[r0 + il];
      }
      __syncthreads();
      int cp = t & 7, rg = t >> 3;   // 8 col-pairs x 32 row-groups
      float2 acc2[BNUM];
      #pragma unroll
      for (int b = 0; b < BNUM; ++b) acc2[b] = make_float2(0.f,0.f);
      const float* wp = Wo + (size_t)(r0 + rg)*DNUM + c0 + cp*2;
      #pragma unroll 4
      for (int it = 0; it < 16; ++it){
        float2 w2 = *(const float2*)wp;
        wp += (size_t)32*DNUM;
        int rr = rg + it*32;
        #pragma unroll
        for (int b = 0; b < BNUM; ++b){
          float xvv = xs[b*512 + rr];
          acc2[b].x += xvv*w2.x; acc2[b].y += xvv*w2.y;
        }
      }
      #pragma unroll
      for (int b = 0; b < BNUM; ++b) red2[(rg*8 + cp)*8 + b] = acc2[b];
      __syncthreads();
      if (t < 64){
        int cpi = t & 7, b = t >> 3;
        float sx = 0.f, sy = 0.f;
        #pragma unroll 8
        for (int rgi = 0; rgi < 32; ++rgi){
          float2 v2 = red2[(rgi*8 + cpi)*8 + b];
          sx += v2.x; sy += v2.y;
        }
        uc_add_f(&P.h[b*DNUM + c0 + cpi*2 + 0], sx);
        uc_add_f(&P.h[b*DNUM + c0 + cpi*2 + 1], sy);
      }
      flag_inc(&P.flagD[li*512 + (blk>>5)*16]);
    }
  }

  // ---- epilogue: final sqp for lm_head ----
  if (blk >= A_TILES && blk < A_TILES + BNUM){
    wait_grp(P.flagD + (LNUM-1)*512, GRID);
    int b = blk - A_TILES;
    float q = 0.f;
    for (int i = t; i < DNUM; i += 256){
      float v = uc_load_f(&P.h[b*DNUM + i]);
      q += v*v;
    }
    q += __shfl_xor(q,32); q += __shfl_xor(q,16); q += __shfl_xor(q,8);
    q += __shfl_xor(q,4);  q += __shfl_xor(q,2);  q += __shfl_xor(q,1);
    if (l == 0) smem[w] = q;
    __syncthreads();
    if (t == 0) uc_store_f(&P.sqp[b], smem[0]+smem[1]+smem[2]+smem[3]);
  }
}

// ---------------- lm_head (final rmsnorm fused), separate launch ----------------
__global__ __launch_bounds__(256) void k_lmhead(const float* __restrict__ h,
                                                const float* __restrict__ sqp,
                                                const float* __restrict__ nf,
                                                const float* __restrict__ Wl,
                                                float* __restrict__ logits){
  __shared__ float hs[BNUM*DNUM];   // 64KB
  __shared__ float invb_s[8];
  int t = threadIdx.x;
  if (t < 8) invb_s[t] = rsqrtf(sqp[t]*(1.f/DNUM) + 1e-5f);
  __syncthreads();
  #pragma unroll
  for (int it = 0; it < 16; ++it){
    int i = t*4 + it*1024;
    float iv = invb_s[it>>1];
    float4 hv  = *(const float4*)(h + i);
    float4 nfv = *(const float4*)(nf + (i & 2047));
    float4 o;
    o.x = hv.x*iv*nfv.x; o.y = hv.y*iv*nfv.y; o.z = hv.z*iv*nfv.z; o.w = hv.w*iv*nfv.w;
    *(float4*)(hs + i) = o;
  }
  __syncthreads();
  int wv = t >> 6, lane = t & 63;
  int v0 = (blockIdx.x*4 + wv)*4;
  float acc[4][BNUM];
  #pragma unroll
  for (int u = 0; u < 4; ++u)
    #pragma unroll
    for (int b = 0; b < BNUM; ++b) acc[u][b] = 0.f;
  #pragma unroll
  for (int j = 0; j < 8; ++j){
    int dbase = j*256 + lane*4;
    float4 w0 = *(const float4*)(Wl + (size_t)(v0+0)*DNUM + dbase);
    float4 w1 = *(const float4*)(Wl + (size_t)(v0+1)*DNUM + dbase);
    float4 w2 = *(const float4*)(Wl + (size_t)(v0+2)*DNUM + dbase);
    float4 w3 = *(const float4*)(Wl + (size_t)(v0+3)*DNUM + dbase);
    #pragma unroll
    for (int b = 0; b < BNUM; ++b){
      float4 hv = *(const float4*)(hs + b*DNUM + dbase);
      acc[0][b] += w0.x*hv.x + w0.y*hv.y + w0.z*hv.z + w0.w*hv.w;
      acc[1][b] += w1.x*hv.x + w1.y*hv.y + w1.z*hv.z + w1.w*hv.w;
      acc[2][b] += w2.x*hv.x + w2.y*hv.y + w2.z*hv.z + w2.w*hv.w;
      acc[3][b] += w3.x*hv.x + w3.y*hv.y + w3.z*hv.z + w3.w*hv.w;
    }
  }
  #pragma unroll
  for (int u = 0; u < 4; ++u)
    #pragma unroll
    for (int b = 0; b < BNUM; ++b){
      float s = acc[u][b];
      s += __shfl_xor(s,32); s += __shfl_xor(s,16); s += __shfl_xor(s,8);
      s += __shfl_xor(s,4);  s += __shfl_xor(s,2);  s += __shfl_xor(s,1);
      if (lane == 0) logits[(size_t)b*VNUM + v0 + u] = s;
    }
}

extern "C" void kernel_launch(void* const* d_in, const int* in_sizes, int n_in,
                              void* d_out, int out_size, void* d_ws, size_t ws_size,
                              hipStream_t stream){
  const int*   ids         = (const int*)d_in[0];
  const float* conv_states = (const float*)d_in[1];
  const float* ssm_states  = (const float*)d_in[2];
  const float* emb         = (const float*)d_in[3];
  const float* norm_w      = (const float*)d_in[4];
  const float* in_proj_w   = (const float*)d_in[5];
  const float* conv_w      = (const float*)d_in[6];
  const float* conv_b      = (const float*)d_in[7];
  const float* dt_bias     = (const float*)d_in[8];
  const float* A_log       = (const float*)d_in[9];
  const float* D_param     = (const float*)d_in[10];
  const float* gn_w        = (const float*)d_in[11];
  const float* out_proj_w  = (const float*)d_in[12];
  const float* norm_f_w    = (const float*)d_in[13];
  const float* lm_head_w   = (const float*)d_in[14];

  float* out         = (float*)d_out;
  float* logits      = out;
  float* conv_out_st = out + (size_t)BNUM*VNUM;
  float* ssm_out_st  = conv_out_st + (size_t)LNUM*BNUM*CONVNUM*KNUM;

  float* ws    = (float*)d_ws;
  float* h     = ws;                   // B*D    = 16384
  float* yg    = h    + 16384;         // B*I    = 32768
  float* ygsq  = yg   + 32768;         // B*128  = 1024
  float* sqp   = ygsq + 1024;          // B (pad 64)
  float* part1 = sqp  + 64;            // 16*B*PNUM = 1318912
  int*   bar   = (int*)(part1 + 1318912);

  // flag layout (all 64B-padded slots, monotonic, memset per launch)
  int* flagE = bar;                 // 16
  int* flagS = flagE + 16;          // 12*16
  int* flagA = flagS + 12*16;       // 12*56*16
  int* flagC = flagA + 12*56*16;    // 12*32*16
  int* flagD = flagC + 12*32*16;    // 12*32*16
  size_t flag_bytes = (size_t)(16 + 12*16 + 12*56*16 + 12*32*16 + 12*32*16) * sizeof(int);
  hipMemsetAsync(bar, 0, flag_bytes, stream);

  MParams P;
  P.ids = ids; P.conv_states = conv_states; P.ssm_states = ssm_states;
  P.emb = emb; P.norm_w = norm_w; P.in_proj_w = in_proj_w;
  P.conv_w = conv_w; P.conv_b = conv_b; P.dt_bias = dt_bias;
  P.A_log = A_log; P.D_param = D_param; P.gn_w = gn_w;
  P.out_proj_w = out_proj_w;
  P.conv_out_st = conv_out_st; P.ssm_out_st = ssm_out_st;
  P.h = h; P.yg = yg; P.ygsq = ygsq; P.sqp = sqp; P.part1 = part1;
  P.flagE = flagE; P.flagS = flagS; P.flagA = flagA; P.flagC = flagC; P.flagD = flagD;

  k_mamba<<<GRID, 256, 0, stream>>>(P);
  k_lmhead<<<VNUM/16, 256, 0, stream>>>(h, sqp, norm_f_w, lm_head_w, logits);
}

// Round 10
// 1164.943 us; speedup vs baseline: 1.1853x; 1.1853x over previous
//
#include <hip/hip_runtime.h>
#include <hip/hip_bf16.h>
#include <math.h>

#define LNUM 12
#define BNUM 8
#define DNUM 2048
#define VNUM 32000
#define HNUM 64
#define HDNUM 64
#define GNUM 8
#define NNUM 128
#define KNUM 4
#define INUM (HNUM*HDNUM)              /* 4096 */
#define CONVNUM (INUM + 2*GNUM*NNUM)   /* 6144 */
#define PNUM (INUM + CONVNUM + HNUM)   /* 10304 */

#define IP_KC 16                       /* in_proj row chunks (128 rows) */
#define NSTRIP 41                      /* ceil(PNUM/256) */
#define A_TILES (NSTRIP*IP_KC)         /* 656 */
#define GRID 1024                      /* 4 blocks/CU resident by construction */

struct MParams {
  const int* ids;
  const float* conv_states; const float* ssm_states;
  const float* emb; const float* norm_w; const float* in_proj_w;
  const float* conv_w; const float* conv_b; const float* dt_bias;
  const float* A_log; const float* D_param; const float* gn_w;
  const float* out_proj_w;
  float* conv_out_st; float* ssm_out_st;
  float* hb0; float* hb1; float* dl0; float* dl1; float* hf;
  float* yg; float* ygsq; float* sqp; float* part1;
  int* arrive; int* release;           // global barrier (R8 two-level)
  int* flagE; int* flagS; int* flagA; int* flagC; int* flagZ;
};

__device__ __forceinline__ float sigmoidf_(float x){ return 1.f/(1.f+expf(-x)); }

// Agent-scope (MALL-direct) accesses — bypass non-coherent per-XCD L2.
__device__ __forceinline__ int   uc_load_i (const int* p){ return __hip_atomic_load((int*)p, __ATOMIC_RELAXED, __HIP_MEMORY_SCOPE_AGENT); }
__device__ __forceinline__ void  uc_store_i(int* p, int v){ __hip_atomic_store(p, v, __ATOMIC_RELAXED, __HIP_MEMORY_SCOPE_AGENT); }
__device__ __forceinline__ float uc_load_f (const float* p){ return __hip_atomic_load((float*)p, __ATOMIC_RELAXED, __HIP_MEMORY_SCOPE_AGENT); }
__device__ __forceinline__ void  uc_store_f(float* p, float v){ __hip_atomic_store(p, v, __ATOMIC_RELAXED, __HIP_MEMORY_SCOPE_AGENT); }
__device__ __forceinline__ void  uc_add_f  (float* p, float v){ __hip_atomic_fetch_add(p, v, __ATOMIC_RELAXED, __HIP_MEMORY_SCOPE_AGENT); }
__device__ __forceinline__ void  uc_inc_i  (int* p){ __hip_atomic_fetch_add(p, 1, __ATOMIC_RELAXED, __HIP_MEMORY_SCOPE_AGENT); }

// Producer: drain this block's stores, one inc on a dedicated line.
__device__ __forceinline__ void flag_inc(int* line){
  __syncthreads();
  if (threadIdx.x == 0){
    asm volatile("s_waitcnt vmcnt(0) lgkmcnt(0)" ::: "memory");
    uc_inc_i(line);
  }
}

// Consumer: single-line poll (cheap, scalable).
__device__ __forceinline__ void poll_line(const int* line, int target){
  long sp = 0;
  while (uc_load_i(line) < target){
    __builtin_amdgcn_s_sleep(4);
    if (++sp > (1L<<20)) break;   // failsafe: wrong answer beats a hang
  }
}
__device__ __forceinline__ void wait_line(const int* line, int target){
  if (threadIdx.x == 0) poll_line(line, target);
  __syncthreads();
}

// R8-proven two-level global barrier: per-block arrival slots, master scan,
// single release store. 13 uses total.
__device__ __forceinline__ void gbar(const MParams& P, int epoch){
  __syncthreads();
  if (blockIdx.x == 0){
    for (int i = 1 + threadIdx.x; i < GRID; i += 256){
      long sp = 0;
      while (uc_load_i(&P.arrive[i*16]) < epoch){
        __builtin_amdgcn_s_sleep(1);
        if (++sp > (1L<<22)) break;
      }
    }
    __syncthreads();
    if (threadIdx.x == 0){
      asm volatile("s_waitcnt vmcnt(0) lgkmcnt(0)" ::: "memory");
      uc_store_i(P.release, epoch);
    }
  } else {
    if (threadIdx.x == 0){
      asm volatile("s_waitcnt vmcnt(0) lgkmcnt(0)" ::: "memory");
      uc_store_i(&P.arrive[blockIdx.x*16], epoch);
      long sp = 0;
      while (uc_load_i(P.release) < epoch){
        __builtin_amdgcn_s_sleep(1);
        if (++sp > (1L<<22)) break;
      }
    }
    __syncthreads();
  }
  asm volatile("" ::: "memory");
}

__global__ __launch_bounds__(256, 4) void k_mamba(MParams P){
  const int blk = blockIdx.x, t = threadIdx.x;
  const int w = t >> 6, l = t & 63;
  __shared__ float smem[3088];   // 12.35 KB, phase-dependent layout
  int ep = 0;

  // ---------------- embed -> hb0 ----------------
  if (blk < BNUM){
    int b = blk;
    const float* src = P.emb + (size_t)P.ids[b]*DNUM;
    float* dst = P.hb0 + (size_t)b*DNUM;
    float4 v0 = *(const float4*)(src + t*4);
    float4 v1 = *(const float4*)(src + 1024 + t*4);
    uc_store_f(dst + t*4 + 0, v0.x); uc_store_f(dst + t*4 + 1, v0.y);
    uc_store_f(dst + t*4 + 2, v0.z); uc_store_f(dst + t*4 + 3, v0.w);
    uc_store_f(dst + 1024 + t*4 + 0, v1.x); uc_store_f(dst + 1024 + t*4 + 1, v1.y);
    uc_store_f(dst + 1024 + t*4 + 2, v1.z); uc_store_f(dst + 1024 + t*4 + 3, v1.w);
    flag_inc(P.flagE);
  }

  for (int li = 0; li < LNUM; ++li){
    const float* Wi   = P.in_proj_w  + (size_t)li*DNUM*PNUM;
    const float* nw   = P.norm_w     + (size_t)li*DNUM;
    const float* cw   = P.conv_w     + (size_t)li*CONVNUM*KNUM;
    const float* cb   = P.conv_b     + (size_t)li*CONVNUM;
    const float* db   = P.dt_bias    + (size_t)li*HNUM;
    const float* al   = P.A_log      + (size_t)li*HNUM;
    const float* dpp  = P.D_param    + (size_t)li*HNUM;
    const float* gw   = P.gn_w       + (size_t)li*INUM;
    const float* Wo   = P.out_proj_w + (size_t)li*INUM*DNUM;
    const float* csin = P.conv_states + (size_t)li*BNUM*CONVNUM*KNUM;
    float*       csout= P.conv_out_st + (size_t)li*BNUM*CONVNUM*KNUM;
    const float* ssin = P.ssm_states  + (size_t)li*BNUM*HNUM*HDNUM*NNUM;
    float*       ssout= P.ssm_out_st  + (size_t)li*BNUM*HNUM*HDNUM*NNUM;

    float* hbase = ((li-1)&1) ? P.hb1 : P.hb0;          // Hin(li-1)-holder; for li=0 -> hb0 via below
    float* hwrite= (li&1) ? P.hb1 : P.hb0;
    float* dprev = ((li-1)&1) ? P.dl1 : P.dl0;
    float* dcur  = (li&1) ? P.dl1 : P.dl0;
    const float* ygsq_prev = P.ygsq + (((li-1)&1) ? 1024 : 0);
    float*       ygsq_cur  = P.ygsq + ((li&1) ? 1024 : 0);
    if (li == 0) hbase = P.hb0;

    // ---- layer entry ----
    if (li == 0) wait_line(P.flagE, BNUM);
    else         gbar(P, ++ep);

    // ---- Phase A: in_proj GEMV on (h + invg*delta)*nw, 1/rms deferred to C ----
    if (blk < A_TILES){
      float*  xs   = smem;                    // 1024
      float*  invs = smem + 1024;             // 8 (+pad to 1040)
      float4* red  = (float4*)(smem + 1040);  // 512 float4
      int pb = blk % NSTRIP, kc = blk / NSTRIP;
      int r0 = kc*128;
      if (li > 0){
        if (t < 64){
          int b2 = t>>3, j = t&7;
          float v = 0.f;
          #pragma unroll
          for (int jj = 0; jj < 16; ++jj) v += uc_load_f(&ygsq_prev[b2*128 + j + jj*8]);
          v += __shfl_xor(v,1); v += __shfl_xor(v,2); v += __shfl_xor(v,4);
          if (j == 0) invs[b2] = rsqrtf(v*(1.f/INUM) + 1e-5f);
        }
        __syncthreads();
        for (int i = t; i < BNUM*128; i += 256){
          int b = i>>7, dl = i&127;
          float hv = uc_load_f(&hbase[b*DNUM + r0 + dl]) + invs[b]*uc_load_f(&dprev[b*DNUM + r0 + dl]);
          xs[i] = hv * nw[r0 + dl];
        }
      } else {
        for (int i = t; i < BNUM*128; i += 256){
          int b = i>>7, dl = i&127;
          xs[i] = uc_load_f(&hbase[b*DNUM + r0 + dl]) * nw[r0 + dl];
        }
      }
      __syncthreads();
      int p0 = pb*256 + l*4;
      bool valid = (p0 < PNUM);
      float4 acc[BNUM];
      #pragma unroll
      for (int b = 0; b < BNUM; ++b) acc[b] = make_float4(0.f,0.f,0.f,0.f);
      if (valid){
        int rbase = w*32;
        const float* wp = Wi + (size_t)(r0 + rbase)*PNUM + p0;
        #pragma unroll 8
        for (int r = 0; r < 32; ++r){
          float4 w4 = *(const float4*)wp;
          wp += PNUM;
          #pragma unroll
          for (int b = 0; b < BNUM; ++b){
            float xvv = xs[b*128 + rbase + r];
            acc[b].x += xvv*w4.x; acc[b].y += xvv*w4.y; acc[b].z += xvv*w4.z; acc[b].w += xvv*w4.w;
          }
        }
      }
      #pragma unroll
      for (int rw = 1; rw < 4; ++rw){
        if (w == rw){
          #pragma unroll
          for (int b = 0; b < BNUM; ++b) red[b*64 + l] = acc[b];
        }
        __syncthreads();
        if (w == 0){
          #pragma unroll
          for (int b = 0; b < BNUM; ++b){
            float4 r4 = red[b*64 + l];
            acc[b].x += r4.x; acc[b].y += r4.y; acc[b].z += r4.z; acc[b].w += r4.w;
          }
        }
        __syncthreads();
      }
      if (w == 0){
        #pragma unroll
        for (int b = 0; b < BNUM; ++b) red[b*64 + l] = acc[b];
      }
      __syncthreads();
      const float* redf = (const float*)red;
      if (pb*256 + t < PNUM){
        #pragma unroll
        for (int b = 0; b < BNUM; ++b)
          uc_store_f(&P.part1[(size_t)(kc*BNUM + b)*PNUM + pb*256 + t], redf[b*256 + t]);
      }
      flag_inc(&P.flagA[(li*NSTRIP + pb)*16]);
    } else if (blk < A_TILES + BNUM){
      // sqp + h materialization
      int b = blk - A_TILES;
      float ivg = 0.f;
      if (li > 0){
        float v = (t < 128) ? uc_load_f(&ygsq_prev[b*128 + t]) : 0.f;
        v += __shfl_xor(v,1); v += __shfl_xor(v,2); v += __shfl_xor(v,4);
        v += __shfl_xor(v,8); v += __shfl_xor(v,16); v += __shfl_xor(v,32);
        if (l == 0) smem[w] = v;
        __syncthreads();
        ivg = rsqrtf((smem[0]+smem[1]+smem[2]+smem[3])*(1.f/INUM) + 1e-5f);
        __syncthreads();
      }
      float q = 0.f;
      for (int i = t; i < DNUM; i += 256){
        float hv;
        if (li > 0){
          hv = uc_load_f(&hbase[b*DNUM + i]) + ivg*uc_load_f(&dprev[b*DNUM + i]);
          uc_store_f(&hwrite[b*DNUM + i], hv);
        } else {
          hv = uc_load_f(&hbase[b*DNUM + i]);
        }
        q += hv*hv;
      }
      q += __shfl_xor(q,32); q += __shfl_xor(q,16); q += __shfl_xor(q,8);
      q += __shfl_xor(q,4);  q += __shfl_xor(q,2);  q += __shfl_xor(q,1);
      if (l == 0) smem[4+w] = q;
      __syncthreads();
      if (t == 0) uc_store_f(&P.sqp[b], smem[4]+smem[5]+smem[6]+smem[7]);
      flag_inc(&P.flagS[li*16]);
    } else if (blk < A_TILES + BNUM + 16){
      // zero the current delta buffer
      int z = blk - A_TILES - BNUM;
      for (int i = t; i < 1024; i += 256) uc_store_f(&dcur[z*1024 + i], 0.f);
      flag_inc(&P.flagZ[li*16]);
    }

    // ---- Phase C: reduce part1 (x inv) + conv/silu/dt + SSM + gate ----
    {
      int b = blk >> 7, rest = blk & 127, hh = rest >> 1, half = rest & 1, g = hh >> 3;
      {
        int s_g  = (hh*HDNUM + half*32) >> 8;
        int s_x  = (INUM + hh*HDNUM + half*32) >> 8;
        int s_B  = (2*INUM + g*NNUM) >> 8;
        int s_C  = (2*INUM + GNUM*NNUM + g*NNUM) >> 8;
        int s_dt = (INUM + CONVNUM) >> 8;
        if      (t == 0) poll_line(&P.flagA[(li*NSTRIP + s_g)*16], IP_KC);
        else if (t == 1) poll_line(&P.flagA[(li*NSTRIP + s_x)*16], IP_KC);
        else if (t == 2) poll_line(&P.flagA[(li*NSTRIP + s_B)*16], IP_KC);
        else if (t == 3) poll_line(&P.flagA[(li*NSTRIP + s_C)*16], IP_KC);
        else if (t == 4) poll_line(&P.flagA[(li*NSTRIP + s_dt)*16], IP_KC);
        else if (t == 5) poll_line(&P.flagS[li*16], BNUM);
        __syncthreads();
      }
      float* xv    = smem;        // 32
      float* gatel = smem + 32;   // 32
      float* Bsh   = smem + 64;   // 128
      float* Csh   = smem + 192;  // 128
      float* scal  = smem + 320;  // [0]=dt [1]=dA [2]=inv
      float* sred  = smem + 328;  // 8
      if (t == 0) scal[2] = rsqrtf(uc_load_f(&P.sqp[b]) * (1.f/DNUM) + 1e-5f);
      __syncthreads();
      float inv = scal[2];
      {
        int n = t & 127;
        int c = (t < 128) ? (INUM + g*NNUM + n) : (INUM + GNUM*NNUM + g*NNUM + n);
        int p = INUM + c;
        float v = 0.f;
        #pragma unroll
        for (int kc2 = 0; kc2 < IP_KC; ++kc2) v += uc_load_f(&P.part1[(size_t)(kc2*BNUM + b)*PNUM + p]);
        v *= inv;
        size_t sid = (size_t)b*CONVNUM + c;
        float4 s4 = *(const float4*)(csin + sid*KNUM);
        float4 ns = make_float4(s4.y, s4.z, s4.w, v);
        if ((hh & 7) == 0 && half == 0) *(float4*)(csout + sid*KNUM) = ns;
        float4 w4 = *(const float4*)(cw + (size_t)c*KNUM);
        float co = ns.x*w4.x + ns.y*w4.y + ns.z*w4.z + ns.w*w4.w + cb[c];
        float sv = co * sigmoidf_(co);
        if (t < 128) Bsh[n] = sv; else Csh[n] = sv;
      }
      if (t < 32){
        int hd = half*32 + t;
        int c = hh*HDNUM + hd;
        int p = INUM + c;
        float v = 0.f;
        #pragma unroll
        for (int kc2 = 0; kc2 < IP_KC; ++kc2) v += uc_load_f(&P.part1[(size_t)(kc2*BNUM + b)*PNUM + p]);
        v *= inv;
        size_t sid = (size_t)b*CONVNUM + c;
        float4 s4 = *(const float4*)(csin + sid*KNUM);
        float4 ns = make_float4(s4.y, s4.z, s4.w, v);
        *(float4*)(csout + sid*KNUM) = ns;
        float4 w4 = *(const float4*)(cw + (size_t)c*KNUM);
        float co = ns.x*w4.x + ns.y*w4.y + ns.z*w4.z + ns.w*w4.w + cb[c];
        xv[t] = co * sigmoidf_(co);
      } else if (t < 64){
        int hd = half*32 + (t-32);
        int p = hh*HDNUM + hd;
        float v = 0.f;
        #pragma unroll
        for (int kc2 = 0; kc2 < IP_KC; ++kc2) v += uc_load_f(&P.part1[(size_t)(kc2*BNUM + b)*PNUM + p]);
        gatel[t-32] = v * inv;
      } else if (t == 64){
        int p = INUM + CONVNUM + hh;
        float v = 0.f;
        #pragma unroll
        for (int kc2 = 0; kc2 < IP_KC; ++kc2) v += uc_load_f(&P.part1[(size_t)(kc2*BNUM + b)*PNUM + p]);
        float dtr = v*inv + db[hh];
        float dt = (dtr > 20.f) ? dtr : log1pf(expf(dtr));
        dt = fminf(dt, 10000.f);
        scal[0] = dt;
        scal[1] = expf(dt * (-expf(al[hh])));
      }
      __syncthreads();
      float dt = scal[0], dA = scal[1], dp = dpp[hh];
      int r = t & 31, a2 = t >> 5;
      float4 Bv = *(float4*)&Bsh[r*4];
      float4 Cv = *(float4*)&Csh[r*4];
      const float* si = ssin  + (size_t)(b*HNUM + hh)*HDNUM*NNUM + half*4096;
      float*       so = ssout + (size_t)(b*HNUM + hh)*HDNUM*NNUM + half*4096;
      float s_yg = 0.f;
      #pragma unroll
      for (int k = 0; k < 4; ++k){
        int hdl = k*8 + a2;
        float xvv = xv[hdl];
        float coef = dt * xvv;
        int off = k*1024 + t*4;
        float4 s4 = *(const float4*)(si + off);
        float4 ns;
        ns.x = s4.x*dA + coef*Bv.x;
        ns.y = s4.y*dA + coef*Bv.y;
        ns.z = s4.z*dA + coef*Bv.z;
        ns.w = s4.w*dA + coef*Bv.w;
        *(float4*)(so + off) = ns;
        float yp = ns.x*Cv.x + ns.y*Cv.y + ns.z*Cv.z + ns.w*Cv.w;
        yp += __shfl_xor(yp,1); yp += __shfl_xor(yp,2); yp += __shfl_xor(yp,4);
        yp += __shfl_xor(yp,8); yp += __shfl_xor(yp,16);
        if (r == 0){
          float gv = gatel[hdl];
          float ygv = (yp + xvv*dp) * gv * sigmoidf_(gv);
          uc_store_f(&P.yg[b*INUM + hh*HDNUM + half*32 + hdl], ygv);
          s_yg += ygv*ygv;
        }
      }
      if (r == 0) sred[a2] = s_yg;
      __syncthreads();
      if (t == 0){
        float tot = 0.f;
        #pragma unroll
        for (int j = 0; j < 8; ++j) tot += sred[j];
        uc_store_f(&ygsq_cur[b*128 + hh*2 + half], tot);
      }
      flag_inc(&P.flagC[(li*HNUM + hh)*16]);
    }

    // ---- Phase D: out_proj GEMV on yg*gw (invg deferred), accumulate delta ----
    {
      int pb = blk & 15, kc = blk >> 4;       // 16 col-strips x 64 heads
      if      (t == 0) poll_line(&P.flagC[(li*HNUM + kc)*16], 16);
      else if (t == 1) poll_line(&P.flagZ[li*16], 16);
      __syncthreads();
      float*  xs   = smem;                     // 512
      float2* red2 = (float2*)(smem + 528);    // 512 float2
      int r0 = kc*64;
      for (int i = t; i < BNUM*64; i += 256){
        int b = i>>6, il = i&63;
        xs[i] = uc_load_f(&P.yg[b*INUM + r0 + il]) * gw[r0 + il];
      }
      __syncthreads();
      int c0 = pb*128 + l*2;
      float2 acc[BNUM];
      #pragma unroll
      for (int b = 0; b < BNUM; ++b) acc[b] = make_float2(0.f,0.f);
      {
        int rbase = w*16;
        const float* wp = Wo + (size_t)(r0 + rbase)*DNUM + c0;
        #pragma unroll 8
        for (int r2 = 0; r2 < 16; ++r2){
          float2 w2 = *(const float2*)wp;
          wp += DNUM;
          #pragma unroll
          for (int b = 0; b < BNUM; ++b){
            float xvv = xs[b*64 + rbase + r2];
            acc[b].x += xvv*w2.x; acc[b].y += xvv*w2.y;
          }
        }
      }
      #pragma unroll
      for (int rw = 1; rw < 4; ++rw){
        if (w == rw){
          #pragma unroll
          for (int b = 0; b < BNUM; ++b) red2[b*64 + l] = acc[b];
        }
        __syncthreads();
        if (w == 0){
          #pragma unroll
          for (int b = 0; b < BNUM; ++b){
            float2 r2v = red2[b*64 + l];
            acc[b].x += r2v.x; acc[b].y += r2v.y;
          }
        }
        __syncthreads();
      }
      if (w == 0){
        #pragma unroll
        for (int b = 0; b < BNUM; ++b) red2[b*64 + l] = acc[b];
      }
      __syncthreads();
      const float* redf = (const float*)red2;   // [b][128]
      #pragma unroll
      for (int bb = 0; bb < 4; ++bb){
        int b = bb*2 + (t>>7);
        int cc = t & 127;
        uc_add_f(&dcur[b*DNUM + pb*128 + cc], redf[b*128 + cc]);
      }
    }
  }

  // ---- final: materialize hf + sqp for lm_head ----
  gbar(P, ++ep);
  if (blk >= A_TILES && blk < A_TILES + BNUM){
    int b = blk - A_TILES;
    const float* ygsq_last = P.ygsq + 1024;   // layer 11 parity = 1
    float v = (t < 128) ? uc_load_f(&ygsq_last[b*128 + t]) : 0.f;
    v += __shfl_xor(v,1); v += __shfl_xor(v,2); v += __shfl_xor(v,4);
    v += __shfl_xor(v,8); v += __shfl_xor(v,16); v += __shfl_xor(v,32);
    if (l == 0) smem[w] = v;
    __syncthreads();
    float ivg = rsqrtf((smem[0]+smem[1]+smem[2]+smem[3])*(1.f/INUM) + 1e-5f);
    __syncthreads();
    float q = 0.f;
    for (int i = t; i < DNUM; i += 256){
      float hv = uc_load_f(&P.hb1[b*DNUM + i]) + ivg*uc_load_f(&P.dl1[b*DNUM + i]);
      P.hf[b*DNUM + i] = hv;
      q += hv*hv;
    }
    q += __shfl_xor(q,32); q += __shfl_xor(q,16); q += __shfl_xor(q,8);
    q += __shfl_xor(q,4);  q += __shfl_xor(q,2);  q += __shfl_xor(q,1);
    if (l == 0) smem[4+w] = q;
    __syncthreads();
    if (t == 0) P.sqp[b] = smem[4]+smem[5]+smem[6]+smem[7];
  }
}

// ---------------- lm_head (final rmsnorm fused), separate launch ----------------
__global__ __launch_bounds__(256) void k_lmhead(const float* __restrict__ hf,
                                                const float* __restrict__ sqp,
                                                const float* __restrict__ nf,
                                                const float* __restrict__ Wl,
                                                float* __restrict__ logits){
  __shared__ float hs[BNUM*DNUM];   // 64KB
  __shared__ float invb_s[8];
  int t = threadIdx.x;
  if (t < 8) invb_s[t] = rsqrtf(sqp[t]*(1.f/DNUM) + 1e-5f);
  __syncthreads();
  #pragma unroll
  for (int it = 0; it < 16; ++it){
    int i = t*4 + it*1024;
    float iv = invb_s[it>>1];
    float4 hv  = *(const float4*)(hf + i);
    float4 nfv = *(const float4*)(nf + (i & 2047));
    float4 o;
    o.x = hv.x*iv*nfv.x; o.y = hv.y*iv*nfv.y; o.z = hv.z*iv*nfv.z; o.w = hv.w*iv*nfv.w;
    *(float4*)(hs + i) = o;
  }
  __syncthreads();
  int wv = t >> 6, lane = t & 63;
  int v0 = (blockIdx.x*4 + wv)*4;
  float acc[4][BNUM];
  #pragma unroll
  for (int u = 0; u < 4; ++u)
    #pragma unroll
    for (int b = 0; b < BNUM; ++b) acc[u][b] = 0.f;
  #pragma unroll
  for (int j = 0; j < 8; ++j){
    int dbase = j*256 + lane*4;
    float4 w0 = *(const float4*)(Wl + (size_t)(v0+0)*DNUM + dbase);
    float4 w1 = *(const float4*)(Wl + (size_t)(v0+1)*DNUM + dbase);
    float4 w2 = *(const float4*)(Wl + (size_t)(v0+2)*DNUM + dbase);
    float4 w3 = *(const float4*)(Wl + (size_t)(v0+3)*DNUM + dbase);
    #pragma unroll
    for (int b = 0; b < BNUM; ++b){
      float4 hv = *(const float4*)(hs + b*DNUM + dbase);
      acc[0][b] += w0.x*hv.x + w0.y*hv.y + w0.z*hv.z + w0.w*hv.w;
      acc[1][b] += w1.x*hv.x + w1.y*hv.y + w1.z*hv.z + w1.w*hv.w;
      acc[2][b] += w2.x*hv.x + w2.y*hv.y + w2.z*hv.z + w2.w*hv.w;
      acc[3][b] += w3.x*hv.x + w3.y*hv.y + w3.z*hv.z + w3.w*hv.w;
    }
  }
  #pragma unroll
  for (int u = 0; u < 4; ++u)
    #pragma unroll
    for (int b = 0; b < BNUM; ++b){
      float s = acc[u][b];
      s += __shfl_xor(s,32); s += __shfl_xor(s,16); s += __shfl_xor(s,8);
      s += __shfl_xor(s,4);  s += __shfl_xor(s,2);  s += __shfl_xor(s,1);
      if (lane == 0) logits[(size_t)b*VNUM + v0 + u] = s;
    }
}

extern "C" void kernel_launch(void* const* d_in, const int* in_sizes, int n_in,
                              void* d_out, int out_size, void* d_ws, size_t ws_size,
                              hipStream_t stream){
  const int*   ids         = (const int*)d_in[0];
  const float* conv_states = (const float*)d_in[1];
  const float* ssm_states  = (const float*)d_in[2];
  const float* emb         = (const float*)d_in[3];
  const float* norm_w      = (const float*)d_in[4];
  const float* in_proj_w   = (const float*)d_in[5];
  const float* conv_w      = (const float*)d_in[6];
  const float* conv_b      = (const float*)d_in[7];
  const float* dt_bias     = (const float*)d_in[8];
  const float* A_log       = (const float*)d_in[9];
  const float* D_param     = (const float*)d_in[10];
  const float* gn_w        = (const float*)d_in[11];
  const float* out_proj_w  = (const float*)d_in[12];
  const float* norm_f_w    = (const float*)d_in[13];
  const float* lm_head_w   = (const float*)d_in[14];

  float* out         = (float*)d_out;
  float* logits      = out;
  float* conv_out_st = out + (size_t)BNUM*VNUM;
  float* ssm_out_st  = conv_out_st + (size_t)LNUM*BNUM*CONVNUM*KNUM;

  float* ws    = (float*)d_ws;
  float* hb0   = ws;                   // B*D
  float* hb1   = hb0  + 16384;
  float* dl0   = hb1  + 16384;
  float* dl1   = dl0  + 16384;
  float* hf    = dl1  + 16384;
  float* yg    = hf   + 16384;         // B*I
  float* ygsq  = yg   + 32768;         // 2 x B*128
  float* sqp   = ygsq + 2048;          // B (pad 64)
  float* part1 = sqp  + 64;            // 16*B*PNUM = 1318912
  int*   bar   = (int*)(part1 + 1318912);

  int* arrive = bar;                      // 1024*16
  int* release= arrive + GRID*16;         // 16
  int* flagE  = release + 16;             // 16
  int* flagS  = flagE + 16;               // 12*16
  int* flagA  = flagS + 12*16;            // 12*41*16
  int* flagC  = flagA + 12*NSTRIP*16;     // 12*64*16
  int* flagZ  = flagC + 12*HNUM*16;       // 12*16
  size_t flag_ints = (size_t)(GRID*16 + 16 + 16 + 12*16 + 12*NSTRIP*16 + 12*HNUM*16 + 12*16);
  hipMemsetAsync(bar, 0, flag_ints*sizeof(int), stream);

  MParams P;
  P.ids = ids; P.conv_states = conv_states; P.ssm_states = ssm_states;
  P.emb = emb; P.norm_w = norm_w; P.in_proj_w = in_proj_w;
  P.conv_w = conv_w; P.conv_b = conv_b; P.dt_bias = dt_bias;
  P.A_log = A_log; P.D_param = D_param; P.gn_w = gn_w;
  P.out_proj_w = out_proj_w;
  P.conv_out_st = conv_out_st; P.ssm_out_st = ssm_out_st;
  P.hb0 = hb0; P.hb1 = hb1; P.dl0 = dl0; P.dl1 = dl1; P.hf = hf;
  P.yg = yg; P.ygsq = ygsq; P.sqp = sqp; P.part1 = part1;
  P.arrive = arrive; P.release = release;
  P.flagE = flagE; P.flagS = flagS; P.flagA = flagA; P.flagC = flagC; P.flagZ = flagZ;

  k_mamba<<<GRID, 256, 0, stream>>>(P);
  k_lmhead<<<VNUM/16, 256, 0, stream>>>(hf, sqp, norm_f_w, lm_head_w, logits);
}